// Round 8
// baseline (336.226 us; speedup 1.0000x reference)
//
#include <hip/hip_runtime.h>

typedef unsigned short u16;
typedef float f32x4 __attribute__((ext_vector_type(4)));
typedef __bf16 bf16x8 __attribute__((ext_vector_type(8)));
typedef u16 u16x8 __attribute__((ext_vector_type(8)));
typedef u16 u16x4 __attribute__((ext_vector_type(4)));

__device__ __forceinline__ u16 f2bf(float f) {
  union { float f; unsigned u; } v; v.f = f;
  unsigned r = (v.u + 0x7FFFu + ((v.u >> 16) & 1u)) >> 16;
  return (u16)r;
}
__device__ __forceinline__ unsigned cvtpk_bf16(float lo, float hi) {
  unsigned r;
  asm("v_cvt_pk_bf16_f32 %0, %1, %2" : "=v"(r) : "v"(lo), "v"(hi));
  return r;
}
__device__ __forceinline__ float wred_sum(float v) {
#pragma unroll
  for (int o = 32; o >= 1; o >>= 1) v += __shfl_xor(v, o);
  return v;
}

// ---------------------------------------------------------------------------
// bf16 MFMA GEMM: C = A[M,K] @ Bt[N,K]^T + bias. Outputs:
//  WF32: f32 [M][N];  WBF: bf16 [M][N];  WVT: bf16 head-transposed [bh][d][s]
// ---------------------------------------------------------------------------
template <int RELU, int WF32, int WBF, int WVT>
__global__ __launch_bounds__(256) void gemm_kernel(
    const u16* __restrict__ A, const u16* __restrict__ Bt,
    const float* __restrict__ bias, float* __restrict__ C,
    u16* __restrict__ Cbf, int M, int N, int K) {
  __shared__ u16 As[64 * 64];
  __shared__ u16 Bs[64 * 64];
  const int tid = threadIdx.x;
  const int lane = tid & 63;
  const int w = tid >> 6;
  const int m0 = blockIdx.x * 64;
  const int n0 = blockIdx.y * 64;
  const int wr = (w >> 1) * 32;
  const int wc = (w & 1) * 32;
  const int l15 = lane & 15, hi = lane >> 4;

  f32x4 acc[2][2] = {};

  for (int k0 = 0; k0 < K; k0 += 64) {
#pragma unroll
    for (int rep = 0; rep < 2; ++rep) {
      int idx = tid + rep * 256;
      int row = idx >> 3, c8 = idx & 7;
      int cs = ((c8 ^ (row & 7)) << 3);
      __builtin_amdgcn_global_load_lds(
          (const __attribute__((address_space(1))) void*)(A + (size_t)(m0 + row) * K + k0 + cs),
          (__attribute__((address_space(3))) void*)(&As[idx * 8]), 16, 0, 0);
      __builtin_amdgcn_global_load_lds(
          (const __attribute__((address_space(1))) void*)(Bt + (size_t)(n0 + row) * K + k0 + cs),
          (__attribute__((address_space(3))) void*)(&Bs[idx * 8]), 16, 0, 0);
    }
    __syncthreads();
#pragma unroll
    for (int kk = 0; kk < 2; ++kk) {
      int kb = (kk * 32 + (hi << 3)) << 1;
      bf16x8 af[2], bfr[2];
#pragma unroll
      for (int mf = 0; mf < 2; ++mf) {
        int m = wr + mf * 16 + l15;
        af[mf] = *(const bf16x8*)((const char*)As + m * 128 + (kb ^ ((m & 7) << 4)));
      }
#pragma unroll
      for (int nf = 0; nf < 2; ++nf) {
        int n = wc + nf * 16 + l15;
        bfr[nf] = *(const bf16x8*)((const char*)Bs + n * 128 + (kb ^ ((n & 7) << 4)));
      }
#pragma unroll
      for (int mf = 0; mf < 2; ++mf)
#pragma unroll
        for (int nf = 0; nf < 2; ++nf)
          acc[mf][nf] = __builtin_amdgcn_mfma_f32_16x16x32_bf16(af[mf], bfr[nf], acc[mf][nf], 0, 0, 0);
    }
    __syncthreads();
  }

#pragma unroll
  for (int mf = 0; mf < 2; ++mf)
#pragma unroll
    for (int nf = 0; nf < 2; ++nf) {
      int col = n0 + wc + nf * 16 + l15;
      float bia = bias[col];
      u16x4 tv;
#pragma unroll
      for (int r = 0; r < 4; ++r) {
        int row = m0 + wr + mf * 16 + (hi << 2) + r;
        float val = acc[mf][nf][r] + bia;
        if (RELU) val = fmaxf(val, 0.f);
        if (WF32) C[(size_t)row * N + col] = val;
        if (WBF) Cbf[(size_t)row * N + col] = f2bf(val);
        if (WVT) tv[r] = f2bf(val);
      }
      if (WVT) {
        int row0 = m0 + wr + mf * 16 + (hi << 2);
        size_t addr = (((size_t)(row0 >> 10) * 8 + (col >> 5)) * 32 + (col & 31)) * 1024 + (row0 & 1023);
        *(u16x4*)(Cbf + addr) = tv;
      }
    }
}

// ---------------------------------------------------------------------------
// Fused K+V projection: A[8192,256] @ WkvT[512,256]^T. Cols 0..255 -> qkbf
// (bf16 row-major, bias bk); cols 256..511 -> vT scatter (bias bv).
// vT must be a valid pointer (V half is always written).
// ---------------------------------------------------------------------------
__global__ __launch_bounds__(256) void gemm_kv_kernel(
    const u16* __restrict__ A, const u16* __restrict__ Bt,
    const float* __restrict__ biasK, const float* __restrict__ biasV,
    u16* __restrict__ qkbf, u16* __restrict__ vT, int M, int N, int K) {
  __shared__ u16 As[64 * 64];
  __shared__ u16 Bs[64 * 64];
  const int tid = threadIdx.x;
  const int lane = tid & 63;
  const int w = tid >> 6;
  const int m0 = blockIdx.x * 64;
  const int n0 = blockIdx.y * 64;
  const int wr = (w >> 1) * 32;
  const int wc = (w & 1) * 32;
  const int l15 = lane & 15, hi = lane >> 4;

  f32x4 acc[2][2] = {};

  for (int k0 = 0; k0 < K; k0 += 64) {
#pragma unroll
    for (int rep = 0; rep < 2; ++rep) {
      int idx = tid + rep * 256;
      int row = idx >> 3, c8 = idx & 7;
      int cs = ((c8 ^ (row & 7)) << 3);
      __builtin_amdgcn_global_load_lds(
          (const __attribute__((address_space(1))) void*)(A + (size_t)(m0 + row) * K + k0 + cs),
          (__attribute__((address_space(3))) void*)(&As[idx * 8]), 16, 0, 0);
      __builtin_amdgcn_global_load_lds(
          (const __attribute__((address_space(1))) void*)(Bt + (size_t)(n0 + row) * K + k0 + cs),
          (__attribute__((address_space(3))) void*)(&Bs[idx * 8]), 16, 0, 0);
    }
    __syncthreads();
#pragma unroll
    for (int kk = 0; kk < 2; ++kk) {
      int kb = (kk * 32 + (hi << 3)) << 1;
      bf16x8 af[2], bfr[2];
#pragma unroll
      for (int mf = 0; mf < 2; ++mf) {
        int m = wr + mf * 16 + l15;
        af[mf] = *(const bf16x8*)((const char*)As + m * 128 + (kb ^ ((m & 7) << 4)));
      }
#pragma unroll
      for (int nf = 0; nf < 2; ++nf) {
        int n = wc + nf * 16 + l15;
        bfr[nf] = *(const bf16x8*)((const char*)Bs + n * 128 + (kb ^ ((n & 7) << 4)));
      }
#pragma unroll
      for (int mf = 0; mf < 2; ++mf)
#pragma unroll
        for (int nf = 0; nf < 2; ++nf)
          acc[mf][nf] = __builtin_amdgcn_mfma_f32_16x16x32_bf16(af[mf], bfr[nf], acc[mf][nf], 0, 0, 0);
    }
    __syncthreads();
  }

  const bool isV = (n0 >= 256);
#pragma unroll
  for (int mf = 0; mf < 2; ++mf)
#pragma unroll
    for (int nf = 0; nf < 2; ++nf) {
      int col = n0 + wc + nf * 16 + l15;
      float bia = isV ? biasV[col - 256] : biasK[col];
      u16x4 tv;
#pragma unroll
      for (int r = 0; r < 4; ++r) {
        int row = m0 + wr + mf * 16 + (hi << 2) + r;
        float val = acc[mf][nf][r] + bia;
        if (!isV) qkbf[(size_t)row * 256 + col] = f2bf(val);
        tv[r] = f2bf(val);
      }
      if (isV) {
        int row0 = m0 + wr + mf * 16 + (hi << 2);
        int vc = col - 256;
        size_t addr = (((size_t)(row0 >> 10) * 8 + (vc >> 5)) * 32 + (vc & 31)) * 1024 + (row0 & 1023);
        *(u16x4*)(vT + addr) = tv;
      }
    }
}

// ---------------------------------------------------------------------------
// MFMA distance-decay attention, butterfly-balanced: block = q-tiles
// (qp, 63-qp) of one (b,h) -> exactly 65 k-tiles/block, all blocks equal.
// 2 waves/block, each takes a contiguous half of the combined tile range;
// per-row cumsum crosses waves via per-context Z-prefix (zbufA/zbufB).
// log2-domain math; masked/padded elements use l=-1000 => P=0 automatically.
// Pass B recomputes the QK MFMA (MFMA pipe idle; avoids register spill).
// ---------------------------------------------------------------------------
__global__ __launch_bounds__(128) void attn_mfma_kernel(
    const u16* __restrict__ qkbf, const u16* __restrict__ vT,
    u16* __restrict__ ao, const float* __restrict__ gam, int excl) {
  __shared__ float zbufA[2][16], zbufB[2][16];
  __shared__ float z2bufA[2][16], z2bufB[2][16];
  __shared__ float accbufA[8][2][64], accbufB[8][2][64];

  const int lane = threadIdx.x & 63, w = threadIdx.x >> 6;  // w in {0,1}
  const int qp = blockIdx.y, bh = blockIdx.x;
  const int b = bh >> 3, h = bh & 7;
  const int qtA = qp, qtB = 63 - qp;
  const int q0A = qtA * 16, q0B = qtB * 16;
  const int l15 = lane & 15, hi = lane >> 4;
  const int iA = q0A + l15, iB = q0B + l15;
  const float LOG2E = 1.4426950408889634f;
  const float g2 = -log1pf(__expf(gam[h])) * LOG2E;      // decay in log2 domain
  const float cscale = 0.17677669529663687f * LOG2E;     // 1/sqrt(32)*log2e
  const float CLIP2 = -16.609640474436812f;              // log2(1e-5)

  const u16* kbase = qkbf + (size_t)b * 1024 * 256 + h * 32;
  const u16* vbase = vT + (size_t)bh * 32 * 1024;
  const bf16x8 qfragA = *(const bf16x8*)(kbase + (size_t)iA * 256 + hi * 8);
  const bf16x8 qfragB = *(const bf16x8*)(kbase + (size_t)iB * 256 + hi * 8);

  const int mylimA = iA - excl, mylimB = iB - excl;
  const int ntA = qtA + 1, ntB = qtB + 1;   // k-tiles per q-tile
  const int ntT = ntA + ntB;                // 65, block-invariant
  const int C = (ntT + 1) >> 1;             // 33 tiles per wave
  const int g0 = w * C;
  const int g1e = g0 + C < ntT ? g0 + C : ntT;
  const int aS = g0 < ntA ? g0 : ntA;
  const int aE = g1e < ntA ? g1e : ntA;
  const int bS = (g0 > ntA ? g0 : ntA) - ntA;
  const int bE = (g1e > ntA ? g1e : ntA) - ntA;

  // QK -> log2-domain scores for one 16-k tile (mask last tile per row)
  auto calc_l = [&](const bf16x8& qf, int t, int lastT, int mylim, float* l) {
    bf16x8 kf = *(const bf16x8*)(kbase + (size_t)(t * 16 + l15) * 256 + hi * 8);
    f32x4 sA = {};
    sA = __builtin_amdgcn_mfma_f32_16x16x32_bf16(kf, qf, sA, 0, 0, 0);
    l[0] = sA[0] * cscale; l[1] = sA[1] * cscale;
    l[2] = sA[2] * cscale; l[3] = sA[3] * cscale;
    if (t == lastT) {                      // wave-uniform
      const int kb = t * 16 + hi * 4;
      l[0] = (kb + 0 <= mylim) ? l[0] : -1000.f;
      l[1] = (kb + 1 <= mylim) ? l[1] : -1000.f;
      l[2] = (kb + 2 <= mylim) ? l[2] : -1000.f;
      l[3] = (kb + 3 <= mylim) ? l[3] : -1000.f;
    }
  };

  // ---- pass A: chunk-partial Z per context ----
  float zA = 0.f, zB = 0.f;
  for (int t = aS; t < aE; ++t) {
    float l[4]; calc_l(qfragA, t, ntA - 1, mylimA, l);
    zA += (exp2f(l[0]) + exp2f(l[1])) + (exp2f(l[2]) + exp2f(l[3]));
  }
  for (int t = bS; t < bE; ++t) {
    float l[4]; calc_l(qfragB, t, ntB - 1, mylimB, l);
    zB += (exp2f(l[0]) + exp2f(l[1])) + (exp2f(l[2]) + exp2f(l[3]));
  }
  zA += __shfl_xor(zA, 16); zA += __shfl_xor(zA, 32);
  zB += __shfl_xor(zB, 16); zB += __shfl_xor(zB, 32);
  if (lane < 16) { zbufA[w][lane] = zA; zbufB[w][lane] = zB; }
  __syncthreads();

  const float zA0 = zbufA[0][l15], zA1 = zbufA[1][l15];
  const float zB0 = zbufB[0][l15], zB1 = zbufB[1][l15];
  const float ZA = zA0 + zA1, ZB = zB0 + zB1;
  const float invZA = ZA > 0.f ? 1.f / ZA : 0.f;
  const float invZB = ZB > 0.f ? 1.f / ZB : 0.f;
  const float prefA = (w > 0) ? zA0 : 0.f;
  const float prefB = (w > 0) ? zB0 : 0.f;

  // cumsum -> decay -> P for one tile (e-domain carry, invZ in decay)
  auto sm4 = [&](const float* l, int kb, int irow, float Z, float invZ,
                 float& carry, float& z2) -> uint2 {
    const float e0 = exp2f(l[0]), e1 = exp2f(l[1]);
    const float e2 = exp2f(l[2]), e3 = exp2f(l[3]);
    const float cA = e0 + e1, cB2 = cA + e2, cC = cB2 + e3;
    float vsc = cC;
    float tmp = __shfl_up(vsc, 16); if (hi >= 1) vsc += tmp;
    tmp = __shfl_up(vsc, 32); if (hi >= 2) vsc += tmp;
    const float exg = vsc - cC;
    const float tot = __shfl(vsc, l15 + 48);
    const float cb = carry + exg;
    carry += tot;
    const float posb = (float)(irow - kb);
    const float r0 = (Z - (cb + e0)) * invZ;
    const float r1 = (Z - (cb + cA)) * invZ;
    const float r2 = (Z - (cb + cB2)) * invZ;
    const float r3 = (Z - (cb + cC)) * invZ;
    const float d20 = fmaxf(r0 * posb, 0.f);
    const float d21 = fmaxf(r1 * (posb - 1.f), 0.f);
    const float d22 = fmaxf(r2 * (posb - 2.f), 0.f);
    const float d23 = fmaxf(r3 * (posb - 3.f), 0.f);
    const float a0 = fmaxf(__builtin_amdgcn_sqrtf(d20) * g2, CLIP2);
    const float a1 = fmaxf(__builtin_amdgcn_sqrtf(d21) * g2, CLIP2);
    const float a2 = fmaxf(__builtin_amdgcn_sqrtf(d22) * g2, CLIP2);
    const float a3 = fmaxf(__builtin_amdgcn_sqrtf(d23) * g2, CLIP2);
    const float p0 = exp2f(l[0] * exp2f(a0));
    const float p1 = exp2f(l[1] * exp2f(a1));
    const float p2 = exp2f(l[2] * exp2f(a2));
    const float p3 = exp2f(l[3] * exp2f(a3));
    z2 += (p0 + p1) + (p2 + p3);
    uint2 r; r.x = cvtpk_bf16(p0, p1); r.y = cvtpk_bf16(p2, p3);
    return r;
  };

  // ---- pass B over one context's chunk: recompute QK, softmax2, PV ----
  auto run_ctx = [&](int s, int e, int lastT, int mylim, const bf16x8& qf,
                     int irow, float Z, float invZ, float& carry, float& z2,
                     f32x4& acc0, f32x4& acc1) {
    for (int t0 = s; t0 < e; t0 += 2) {
      const int t1 = t0 + 1;
      float la[4], lb[4];
      calc_l(qf, t0, lastT, mylim, la);
      const bool v1 = (t1 < e);            // wave-uniform
      if (v1) calc_l(qf, t1, lastT, mylim, lb);
      uint2 uA = sm4(la, t0 * 16 + hi * 4, irow, Z, invZ, carry, z2);
      uint2 uB = make_uint2(0u, 0u);
      if (v1) uB = sm4(lb, t1 * 16 + hi * 4, irow, Z, invZ, carry, z2);
      // regroup C-layout P^T (k=hi*4+r) into B-frag (k=hi*8..hi*8+7) over 32 k
      const int srcA = l15 + (((2 * hi) & 3) << 4);
      const int srcB = l15 + (((2 * hi + 1) & 3) << 4);
      unsigned a00 = (unsigned)__shfl((int)uA.x, srcA);
      unsigned a01 = (unsigned)__shfl((int)uB.x, srcA);
      unsigned a10 = (unsigned)__shfl((int)uA.y, srcA);
      unsigned a11 = (unsigned)__shfl((int)uB.y, srcA);
      unsigned b00 = (unsigned)__shfl((int)uA.x, srcB);
      unsigned b01 = (unsigned)__shfl((int)uB.x, srcB);
      unsigned b10 = (unsigned)__shfl((int)uA.y, srcB);
      unsigned b11 = (unsigned)__shfl((int)uB.y, srcB);
      const bool up = hi >= 2;
      union { unsigned u[4]; bf16x8 v; } pf;
      pf.u[0] = up ? a01 : a00;
      pf.u[1] = up ? a11 : a10;
      pf.u[2] = up ? b01 : b00;
      pf.u[3] = up ? b11 : b10;
      const int jb = t0 * 16;
      bf16x8 vf0 = *(const bf16x8*)(vbase + (size_t)l15 * 1024 + jb + hi * 8);
      bf16x8 vf1 = *(const bf16x8*)(vbase + (size_t)(16 + l15) * 1024 + jb + hi * 8);
      acc0 = __builtin_amdgcn_mfma_f32_16x16x32_bf16(vf0, pf.v, acc0, 0, 0, 0);
      acc1 = __builtin_amdgcn_mfma_f32_16x16x32_bf16(vf1, pf.v, acc1, 0, 0, 0);
    }
  };

  float carryA = prefA, z2A = 0.f, carryB = prefB, z2B = 0.f;
  f32x4 aA0 = {}, aA1 = {}, aB0 = {}, aB1 = {};
  run_ctx(aS, aE, ntA - 1, mylimA, qfragA, iA, ZA, invZA, carryA, z2A, aA0, aA1);
  run_ctx(bS, bE, ntB - 1, mylimB, qfragB, iB, ZB, invZB, carryB, z2B, aB0, aB1);

  z2A += __shfl_xor(z2A, 16); z2A += __shfl_xor(z2A, 32);
  z2B += __shfl_xor(z2B, 16); z2B += __shfl_xor(z2B, 32);
  if (lane < 16) { z2bufA[w][lane] = z2A; z2bufB[w][lane] = z2B; }
#pragma unroll
  for (int j = 0; j < 4; ++j) {
    accbufA[j][w][lane] = aA0[j];
    accbufA[4 + j][w][lane] = aA1[j];
    accbufB[j][w][lane] = aB0[j];
    accbufB[4 + j][w][lane] = aB1[j];
  }
  __syncthreads();

  {
    const bool isA = (w == 0);                 // wave 0 -> A rows, wave 1 -> B
    float (*z2p)[16] = isA ? z2bufA : z2bufB;
    float (*accp)[2][64] = isA ? accbufA : accbufB;
    const int irow = isA ? iA : iB;
    const float z2t = z2p[0][l15] + z2p[1][l15];
    const float inv2 = z2t > 0.f ? 1.f / z2t : 0.f;  // 0 => excl row 0 (zero_pad)
    u16* aop = ao + ((size_t)(b * 1024 + irow)) * 256 + h * 32;
    float s0[4], s1[4];
#pragma unroll
    for (int j = 0; j < 4; ++j) {
      s0[j] = (accp[j][0][lane] + accp[j][1][lane]) * inv2;
      s1[j] = (accp[4 + j][0][lane] + accp[4 + j][1][lane]) * inv2;
    }
    uint2 o0, o1;
    o0.x = cvtpk_bf16(s0[0], s0[1]); o0.y = cvtpk_bf16(s0[2], s0[3]);
    o1.x = cvtpk_bf16(s1[0], s1[1]); o1.y = cvtpk_bf16(s1[2], s1[3]);
    *(uint2*)(aop + hi * 4) = o0;
    *(uint2*)(aop + 16 + hi * 4) = o1;
  }
}

// ---------------------------------------------------------------------------
__global__ __launch_bounds__(256) void add_ln_kernel(
    const float* __restrict__ res, const float* __restrict__ add,
    const float* __restrict__ g, const float* __restrict__ b,
    float* __restrict__ outf, u16* __restrict__ outb) {
  const int lane = threadIdx.x & 63, wid = threadIdx.x >> 6;
  const size_t row = (size_t)blockIdx.x * 4 + wid;
  const size_t base = row * 256 + lane * 4;
  float4 rv = *(const float4*)(res + base);
  float4 av = *(const float4*)(add + base);
  float x0 = rv.x + av.x, x1 = rv.y + av.y, x2 = rv.z + av.z, x3 = rv.w + av.w;
  float sm = wred_sum(x0 + x1 + x2 + x3);
  float mu = sm * (1.f / 256.f);
  float d0 = x0 - mu, d1 = x1 - mu, d2 = x2 - mu, d3 = x3 - mu;
  float vs = wred_sum(d0 * d0 + d1 * d1 + d2 * d2 + d3 * d3);
  float rs = rsqrtf(vs * (1.f / 256.f) + 1e-5f);
  float4 gv = *(const float4*)(g + lane * 4);
  float4 bv = *(const float4*)(b + lane * 4);
  float o0 = d0 * rs * gv.x + bv.x;
  float o1 = d1 * rs * gv.y + bv.y;
  float o2 = d2 * rs * gv.z + bv.z;
  float o3 = d3 * rs * gv.w + bv.w;
  float4 ov = {o0, o1, o2, o3};
  *(float4*)(outf + base) = ov;
  u16x4 wv; wv[0] = f2bf(o0); wv[1] = f2bf(o1); wv[2] = f2bf(o2); wv[3] = f2bf(o3);
  *(u16x4*)(outb + base) = wv;
}

__global__ __launch_bounds__(256) void cast_bf_kernel(
    const float* __restrict__ in, u16* __restrict__ out) {
  size_t i = ((size_t)blockIdx.x * 256 + threadIdx.x) * 8;
  float4 a = *(const float4*)(in + i);
  float4 c = *(const float4*)(in + i + 4);
  u16x8 o;
  o[0] = f2bf(a.x); o[1] = f2bf(a.y); o[2] = f2bf(a.z); o[3] = f2bf(a.w);
  o[4] = f2bf(c.x); o[5] = f2bf(c.y); o[6] = f2bf(c.z); o[7] = f2bf(c.w);
  *(u16x8*)(out + i) = o;
}

// Wt[z*dstStride + n*K + k] = bf16(W[z*K*N + k*N + n])
__global__ __launch_bounds__(256) void transpose_cast_kernel(
    const float* __restrict__ W, u16* __restrict__ Wt, int K, int N,
    int dstStride) {
  __shared__ float t[32][33];
  const size_t lo = (size_t)blockIdx.z * K * N;
  const size_t lod = (size_t)blockIdx.z * dstStride;
  int n0 = blockIdx.x * 32, k0 = blockIdx.y * 32;
  int tx = threadIdx.x, ty = threadIdx.y;  // 32 x 8
#pragma unroll
  for (int r = 0; r < 32; r += 8)
    t[ty + r][tx] = W[lo + (size_t)(k0 + ty + r) * N + n0 + tx];
  __syncthreads();
#pragma unroll
  for (int r = 0; r < 32; r += 8)
    Wt[lod + (size_t)(n0 + ty + r) * K + k0 + tx] = f2bf(t[tx][ty + r]);
}

// ---------------------------------------------------------------------------
extern "C" void kernel_launch(void* const* d_in, const int* in_sizes, int n_in,
                              void* d_out, int out_size, void* d_ws,
                              size_t ws_size, hipStream_t stream) {
  const float* q_embed = (const float*)d_in[0];
  const float* qa_embed = (const float*)d_in[1];
  const float* Wk = (const float*)d_in[2];
  const float* bk = (const float*)d_in[3];
  const float* Wv = (const float*)d_in[4];
  const float* bv = (const float*)d_in[5];
  const float* Wo = (const float*)d_in[6];
  const float* bo = (const float*)d_in[7];
  const float* gammas = (const float*)d_in[8];
  const float* ln1_g = (const float*)d_in[9];
  const float* ln1_b = (const float*)d_in[10];
  const float* W1 = (const float*)d_in[11];
  const float* b1 = (const float*)d_in[12];
  const float* W2 = (const float*)d_in[13];
  const float* b2 = (const float*)d_in[14];
  const float* ln2_g = (const float*)d_in[15];
  const float* ln2_b = (const float*)d_in[16];

  const size_t ACT_F32 = (size_t)8192 * 256 * 4;  // 8 MB
  const size_t ACT_BF = (size_t)8192 * 256 * 2;   // 4 MB
  char* p = (char*)d_ws;
  auto carve = [&](size_t bytes) {
    void* r = (void*)p;
    p += (bytes + 255) & ~(size_t)255;
    return r;
  };
  float* yb = (float*)carve(ACT_F32);
  float* xb = (float*)carve(ACT_F32);
  float* pof = (float*)carve(ACT_F32);
  u16* xbf = (u16*)carve(ACT_BF);
  u16* ybf = (u16*)carve(ACT_BF);
  u16* qkbf = (u16*)carve(ACT_BF);
  u16* vTb = (u16*)carve(ACT_BF);
  u16* aobf = (u16*)carve(ACT_BF);
  u16* hbf = (u16*)carve((size_t)8192 * 1024 * 2);  // 16 MB
  u16* Wkvt = (u16*)carve((size_t)3 * 131072 * 2);
  u16* Wot = (u16*)carve((size_t)3 * 65536 * 2);
  u16* W1t = (u16*)carve((size_t)3 * 262144 * 2);
  u16* W2t = (u16*)carve((size_t)3 * 262144 * 2);

  dim3 tb(32, 8);
  transpose_cast_kernel<<<dim3(8, 8, 3), tb, 0, stream>>>(Wk, Wkvt, 256, 256, 131072);
  transpose_cast_kernel<<<dim3(8, 8, 3), tb, 0, stream>>>(Wv, Wkvt + 65536, 256, 256, 131072);
  transpose_cast_kernel<<<dim3(8, 8, 3), tb, 0, stream>>>(Wo, Wot, 256, 256, 65536);
  transpose_cast_kernel<<<dim3(32, 8, 3), tb, 0, stream>>>(W1, W1t, 256, 1024, 262144);
  transpose_cast_kernel<<<dim3(8, 32, 3), tb, 0, stream>>>(W2, W2t, 1024, 256, 262144);
  cast_bf_kernel<<<1024, 256, 0, stream>>>(q_embed, xbf);
  cast_bf_kernel<<<1024, 256, 0, stream>>>(qa_embed, ybf);

  const dim3 gP(128, 4), gF(128, 16), gKV(128, 8);
  const dim3 gA(64, 32);

  // ---- block 0: layer 0, y = qa, incl mask, FFN ----
  gemm_kv_kernel<<<gKV, 256, 0, stream>>>(ybf, Wkvt, bk, bv, qkbf, vTb, 8192, 512, 256);
  attn_mfma_kernel<<<gA, 128, 0, stream>>>(qkbf, vTb, aobf, gammas, 0);
  gemm_kernel<0, 1, 0, 0><<<gP, 256, 0, stream>>>(aobf, Wot, bo, pof, nullptr, 8192, 256, 256);
  add_ln_kernel<<<2048, 256, 0, stream>>>(qa_embed, pof, ln1_g, ln1_b, yb, ybf);
  gemm_kernel<1, 0, 1, 0><<<gF, 256, 0, stream>>>(ybf, W1t, b1, nullptr, hbf, 8192, 1024, 256);
  gemm_kernel<0, 1, 0, 0><<<gP, 256, 0, stream>>>(hbf, W2t, b2, pof, nullptr, 8192, 256, 1024);
  add_ln_kernel<<<2048, 256, 0, stream>>>(yb, pof, ln2_g, ln2_b, yb, ybf);

  // ---- block 1: layer 1, x = q_embed, incl mask, no FFN ----
  gemm_kv_kernel<<<gKV, 256, 0, stream>>>(xbf, Wkvt + 131072, bk + 256, bv + 256, qkbf, vTb, 8192, 512, 256);
  attn_mfma_kernel<<<gA, 128, 0, stream>>>(qkbf, vTb, aobf, gammas + 8, 0);
  gemm_kernel<0, 1, 0, 0><<<gP, 256, 0, stream>>>(aobf, Wot + 65536, bo + 256, pof, nullptr, 8192, 256, 256);
  add_ln_kernel<<<2048, 256, 0, stream>>>(q_embed, pof, ln1_g + 256, ln1_b + 256, xb, xbf);

  // ---- block 2: layer 2, q/k from x, v from y, excl mask (zero_pad natural) ----
  // Fused KV writes V(x) into vTb (garbage), then the V(y) GEMM fully
  // overwrites vTb before attention reads it (same stream => ordered).
  gemm_kv_kernel<<<gKV, 256, 0, stream>>>(xbf, Wkvt + 262144, bk + 512, bv + 512, qkbf, vTb, 8192, 512, 256);
  gemm_kernel<0, 0, 0, 1><<<gP, 256, 0, stream>>>(ybf, Wkvt + 262144 + 65536, bv + 512, nullptr, vTb, 8192, 256, 256);
  attn_mfma_kernel<<<gA, 128, 0, stream>>>(qkbf, vTb, aobf, gammas + 16, 1);
  gemm_kernel<0, 1, 0, 0><<<gP, 256, 0, stream>>>(aobf, Wot + 131072, bo + 512, pof, nullptr, 8192, 256, 256);
  add_ln_kernel<<<2048, 256, 0, stream>>>(xb, pof, ln1_g + 512, ln1_b + 512, xb, xbf);
  gemm_kernel<1, 0, 1, 0><<<gF, 256, 0, stream>>>(xbf, W1t + 524288, b1 + 2048, nullptr, hbf, 8192, 1024, 256);
  gemm_kernel<0, 1, 0, 0><<<gP, 256, 0, stream>>>(hbf, W2t + 524288, b2 + 512, pof, nullptr, 8192, 256, 1024);
  add_ln_kernel<<<2048, 256, 0, stream>>>(xb, pof, ln2_g + 512, ln2_b + 512, (float*)d_out, xbf);
}